// Round 3
// baseline (892.657 us; speedup 1.0000x reference)
//
#include <hip/hip_runtime.h>
#include <float.h>

// QueryPooling: x[B,L,C] f32, mask[B,L] i32, queries[K,C] f32 -> out[B,K,C] f32
// B=16 L=4096 C=1024 K=16. scale = C^-0.5 = 1/32.
#define NB 16
#define NL 4096
#define NC 1024
#define NK 16
// scale * log2(e)
#define SC2 0.04508422f

__device__ __forceinline__ float4 ld4(const float* p) { return *(const float4*)p; }

// async global->LDS, 16B per lane. LDS dest is wave-uniform base + lane*16.
__device__ __forceinline__ void gload16(const float* g, float* l) {
  __builtin_amdgcn_global_load_lds(
      (const __attribute__((address_space(1))) void*)g,
      (__attribute__((address_space(3))) void*)l, 16, 0, 0);
}

__device__ __forceinline__ void barrier_raw() {
  asm volatile("" ::: "memory");
  __builtin_amdgcn_s_barrier();
  asm volatile("" ::: "memory");
}

// ---------------------------------------------------------------------------
// Kernel 1: fused scores + online softmax + PV. Wave-local end-to-end:
// wave w owns queries 4w..4w+4 (scores, softmax, PV) so the only cross-wave
// syncs are the TWO staging barriers per 8-row sub-chunk (A: buf free,
// B: buf staged). Softmax runs fully in-register per wave; the 32 weights
// are exchanged via a per-wave LDS slot guarded by lgkmcnt(0) only.
//
//   NSC=16 -> 128-row slabs, grid 512, 2 blocks/CU (fast path)
//   NSC=32 -> 256-row slabs, grid 256 (ws-size fallback)
//
// Butterfly output mapping (verified in R2): lane holds reduced value for
// vi = bitrev5(lane&31) = kk*8+j, i.e. kk = ((lane&1)<<1)|((lane&2)>>1),
// j = (lane&4)|((lane&8)>>2)|((lane&16)>>4); lanes 32-63 duplicate.
// j varies with lane bits 2/3/4 -> row reductions are shfl_xor 4/8/16.
// LDS: Xs[2][8][1024] 64KB + WtW[4][32] + Ms -> ~66 KB, 2 blocks/CU.
// ---------------------------------------------------------------------------
template<int NSC>
__global__ __launch_bounds__(256, 2)
void qpool_partial(const float* __restrict__ X, const int* __restrict__ Mk,
                   const float* __restrict__ Q, float* __restrict__ Op,
                   float* __restrict__ MSp) {
  constexpr int ROWS  = NSC * 8;
  constexpr int SLABS = NL / ROWS;

  __shared__ float Xs[2 * 8 * 1024];
  __shared__ float WtW[4 * 32];     // per-wave weight slot: [wid][kk*8+j]
  __shared__ int   Ms[ROWS];

  const int tid  = threadIdx.x;
  const int lane = tid & 63;
  const int wid  = tid >> 6;
  const int blk  = blockIdx.x;
  const int b    = blk / SLABS;
  const int l0   = (blk % SLABS) * ROWS;

  const float* Xb = X + (size_t)b * NL * NC;
  const int*   Mb = Mk + (size_t)b * NL;

  // ---- prologue: issue sub-chunk 0 staging (8 vmem ops/thread) ----
  {
    const float* g0 = Xb + (size_t)l0 * NC + (wid * 256 + lane * 4);
#pragma unroll
    for (int j = 0; j < 8; ++j)
      gload16(g0 + (size_t)j * NC, &Xs[j * 1024 + wid * 256]);
  }

  // ---- Q fragment: 4 queries x 16 c-floats (granule m*64+lane) = 64 VGPR ----
  float4 qr[4][4];
#pragma unroll
  for (int kk = 0; kk < 4; ++kk)
#pragma unroll
    for (int m = 0; m < 4; ++m)
      qr[kk][m] = ld4(Q + (size_t)(wid * 4 + kk) * NC + (m * 64 + lane) * 4);

  if (tid < ROWS) Ms[tid] = Mb[l0 + tid];

  // butterfly value index for this lane
  const int vi = ((lane & 1) << 4) | ((lane & 2) << 2) | (lane & 4) |
                 ((lane & 8) >> 2) | ((lane & 16) >> 4);
  const int kkL = vi >> 3;        // this lane's query (within wave) after reduce
  const int jL  = vi & 7;         // this lane's row after reduce

  // per-lane running softmax state for query kkL (replicated over 16 lanes)
  float m_run = -FLT_MAX, s_run = 0.f;

  // PV accumulators: o[kk][m] = query kk, c-granule m*64+lane
  float4 o[4][4];
#pragma unroll
  for (int kk = 0; kk < 4; ++kk)
#pragma unroll
    for (int m = 0; m < 4; ++m) o[kk][m] = make_float4(0.f, 0.f, 0.f, 0.f);

  for (int sc = 0; sc < NSC; ++sc) {
    const int buf = sc & 1;
    float* Xc = &Xs[buf * 8 * 1024];

    barrier_raw();                                  // A: buf^1's readers done
    if (sc + 1 < NSC) {
      const float* gn = Xb + (size_t)(l0 + (sc + 1) * 8) * NC + (wid * 256 + lane * 4);
      float* ln = &Xs[(buf ^ 1) * 8 * 1024 + wid * 256];
#pragma unroll
      for (int j = 0; j < 8; ++j)
        gload16(gn + (size_t)j * NC, ln + j * 1024);
      asm volatile("s_waitcnt vmcnt(8) lgkmcnt(0)" ::: "memory");
    } else {
      asm volatile("s_waitcnt vmcnt(0) lgkmcnt(0)" ::: "memory");
    }
    barrier_raw();                                  // B: buf fully staged

    // ---- phase 1: partial scores over this lane's 16 c-columns ----
    float acc[4][8];
#pragma unroll
    for (int kk = 0; kk < 4; ++kk)
#pragma unroll
      for (int j = 0; j < 8; ++j) acc[kk][j] = 0.f;

#pragma unroll
    for (int m = 0; m < 4; ++m) {
#pragma unroll
      for (int j = 0; j < 8; ++j) {
        const float4 xv = ld4(&Xc[j * 1024 + (m * 64 + lane) * 4]);
#pragma unroll
        for (int kk = 0; kk < 4; ++kk) {
          float a = acc[kk][j];
          a = fmaf(xv.x, qr[kk][m].x, a);
          a = fmaf(xv.y, qr[kk][m].y, a);
          a = fmaf(xv.z, qr[kk][m].z, a);
          a = fmaf(xv.w, qr[kk][m].w, a);
          acc[kk][j] = a;
        }
      }
    }

    // ---- value-splitting butterfly: 32 values over 64 lanes, 32 shfls ----
    float v[32];
#pragma unroll
    for (int kk = 0; kk < 4; ++kk)
#pragma unroll
      for (int j = 0; j < 8; ++j) v[kk * 8 + j] = acc[kk][j];
#pragma unroll
    for (int p = 0; p < 5; ++p) {
      const int  mm   = 1 << p;
      const int  half = 16 >> p;
      const bool hi   = (lane & mm) != 0;
#pragma unroll
      for (int i = 0; i < half; ++i) {
        const float send = hi ? v[i] : v[half + i];
        const float keep = hi ? v[half + i] : v[i];
        v[i] = keep + __shfl_xor(send, mm, 64);
      }
    }
    v[0] += __shfl_xor(v[0], 32, 64);
    const float sraw = v[0];                 // score(query kkL, row jL)

    // ---- wave-local online softmax (all in registers) ----
    const int msk = Ms[sc * 8 + jL];
    float cmax = msk ? sraw : -FLT_MAX;
    cmax = fmaxf(cmax, __shfl_xor(cmax, 4, 64));
    cmax = fmaxf(cmax, __shfl_xor(cmax, 8, 64));
    cmax = fmaxf(cmax, __shfl_xor(cmax, 16, 64));
    const float mnew  = fmaxf(m_run, cmax);
    const float e     = msk ? exp2f((sraw - mnew) * SC2) : 0.f;
    float csum = e;
    csum += __shfl_xor(csum, 4, 64);
    csum += __shfl_xor(csum, 8, 64);
    csum += __shfl_xor(csum, 16, 64);
    const float alpha = exp2f((m_run - mnew) * SC2);   // ==1 when no change
    s_run = s_run * alpha + csum;
    m_run = mnew;

    // share the 32 weights within the wave (no barrier: lgkmcnt only)
    if (lane < 32) WtW[wid * 32 + vi] = e;
    asm volatile("s_waitcnt lgkmcnt(0)" ::: "memory");
    float4 wv0[4], wv1[4];
#pragma unroll
    for (int kk = 0; kk < 4; ++kk) {
      wv0[kk] = ld4(&WtW[wid * 32 + kk * 8]);
      wv1[kk] = ld4(&WtW[wid * 32 + kk * 8 + 4]);
    }
    float w8[4][8];
#pragma unroll
    for (int kk = 0; kk < 4; ++kk) {
      w8[kk][0] = wv0[kk].x; w8[kk][1] = wv0[kk].y;
      w8[kk][2] = wv0[kk].z; w8[kk][3] = wv0[kk].w;
      w8[kk][4] = wv1[kk].x; w8[kk][5] = wv1[kk].y;
      w8[kk][6] = wv1[kk].z; w8[kk][7] = wv1[kk].w;
    }
    // alpha for kk lives on lane {0,2,1,3}[kk]
    float a4[4];
    a4[0] = __shfl(alpha, 0, 64);
    a4[1] = __shfl(alpha, 2, 64);
    a4[2] = __shfl(alpha, 1, 64);
    a4[3] = __shfl(alpha, 3, 64);

    // ---- PV: rescale + accumulate ----
#pragma unroll
    for (int kk = 0; kk < 4; ++kk)
#pragma unroll
      for (int m = 0; m < 4; ++m) {
        o[kk][m].x *= a4[kk]; o[kk][m].y *= a4[kk];
        o[kk][m].z *= a4[kk]; o[kk][m].w *= a4[kk];
      }
#pragma unroll
    for (int l = 0; l < 8; ++l) {
#pragma unroll
      for (int m = 0; m < 4; ++m) {
        const float4 xv = ld4(&Xc[l * 1024 + (m * 64 + lane) * 4]);
#pragma unroll
        for (int kk = 0; kk < 4; ++kk) {
          const float wk = w8[kk][l];
          o[kk][m].x = fmaf(wk, xv.x, o[kk][m].x);
          o[kk][m].y = fmaf(wk, xv.y, o[kk][m].y);
          o[kk][m].z = fmaf(wk, xv.z, o[kk][m].z);
          o[kk][m].w = fmaf(wk, xv.w, o[kk][m].w);
        }
      }
    }
  }

  // ---- epilogue: slab partials (coalesced per wave) ----
  float* Ob = Op + (size_t)blk * NK * NC;
#pragma unroll
  for (int kk = 0; kk < 4; ++kk)
#pragma unroll
    for (int m = 0; m < 4; ++m)
      *(float4*)(Ob + (size_t)(wid * 4 + kk) * NC + (m * 64 + lane) * 4) = o[kk][m];
  // (m,s) for query kkL lives on lanes 0..3 (j==0 there)
  if (lane < 4) {
    MSp[(blk * 16 + wid * 4 + kkL) * 2]     = m_run;
    MSp[(blk * 16 + wid * 4 + kkL) * 2 + 1] = s_run;
  }
}

// ---------------------------------------------------------------------------
// Kernel 2: merge SLABS partials per (b,k) with max-rescale + normalize.
// grid 256 (one per (b,k)), 256 threads. All-masked rows -> denom 0 -> zeros.
// ---------------------------------------------------------------------------
template<int SLABS>
__global__ __launch_bounds__(256, 2)
void qpool_combine(const float* __restrict__ Op, const float* __restrict__ MSp,
                   float* __restrict__ Out) {
  const int bk = blockIdx.x;
  const int b = bk >> 4, k = bk & 15;
  const int tid = threadIdx.x;

  float m[SLABS], s[SLABS], f[SLABS];
  float M = -FLT_MAX;
#pragma unroll
  for (int lb = 0; lb < SLABS; ++lb) {
    m[lb] = MSp[((b * SLABS + lb) * 16 + k) * 2];
    s[lb] = MSp[((b * SLABS + lb) * 16 + k) * 2 + 1];
    M = fmaxf(M, m[lb]);
  }
  float denom = 0.f;
#pragma unroll
  for (int lb = 0; lb < SLABS; ++lb) {
    f[lb] = exp2f((m[lb] - M) * SC2);
    denom += s[lb] * f[lb];
  }
  float4 acc = make_float4(0.f, 0.f, 0.f, 0.f);
#pragma unroll
  for (int lb = 0; lb < SLABS; ++lb) {
    const float4 v = ld4(Op + ((size_t)(b * SLABS + lb) * 16 + k) * NC + tid * 4);
    acc.x = fmaf(f[lb], v.x, acc.x);
    acc.y = fmaf(f[lb], v.y, acc.y);
    acc.z = fmaf(f[lb], v.z, acc.z);
    acc.w = fmaf(f[lb], v.w, acc.w);
  }
  const float inv = denom > 0.f ? 1.f / denom : 0.f;
  acc.x *= inv; acc.y *= inv; acc.z *= inv; acc.w *= inv;
  *(float4*)(Out + (size_t)bk * NC + tid * 4) = acc;
}

extern "C" void kernel_launch(void* const* d_in, const int* in_sizes, int n_in,
                              void* d_out, int out_size, void* d_ws, size_t ws_size,
                              hipStream_t stream) {
  const float* X  = (const float*)d_in[0];
  const int*   Mk = (const int*)d_in[1];
  const float* Q  = (const float*)d_in[2];
  float* Out = (float*)d_out;

  const size_t need512 = ((size_t)512 * NK * NC + (size_t)512 * NK * 2) * sizeof(float);
  if (ws_size >= need512) {
    float* Op  = (float*)d_ws;
    float* MSp = Op + (size_t)512 * NK * NC;
    qpool_partial<16><<<512, 256, 0, stream>>>(X, Mk, Q, Op, MSp);
    qpool_combine<32><<<256, 256, 0, stream>>>(Op, MSp, Out);
  } else {
    float* Op  = (float*)d_ws;
    float* MSp = Op + (size_t)256 * NK * NC;
    qpool_partial<32><<<256, 256, 0, stream>>>(X, Mk, Q, Op, MSp);
    qpool_combine<16><<<256, 256, 0, stream>>>(Op, MSp, Out);
  }
}